// Round 2
// baseline (606.388 us; speedup 1.0000x reference)
//
#include <hip/hip_runtime.h>
#include <hip/hip_bf16.h>
#include <cstdint>
#include <cstddef>

// WaveKAN FFN: B=4 S=2048 D=1024 H=4096, M = B*S = 8192.
// layer1: h = mexhat((x-t1)/s1) @ wav_w1^T + silu(x) @ base_w1^T   [M,H]
// layer2: out = mexhat((h-t2)/s2) @ wav_w2^T + silu(h) @ base_w2^T [M,D]
// Concat branch-GEMMs along K (K1=2048, K2=8192), bf16 MFMA, fp32 accum.
// Layer-2 activations fused into GEMM1 epilogue (h never materialized).
// R2: inner loop switched 16x16x32 -> 32x32x16 MFMA (2x2 tiles/wave):
// halves MFMA instruction count per BK, same ds_read count, same LDS layout.

typedef __bf16 bf16x8 __attribute__((ext_vector_type(8)));
typedef float  f32x16 __attribute__((ext_vector_type(16)));

#define MH_C 0.8673250705840776f   // 2/sqrt(3) * pi^-0.25

__device__ __forceinline__ float mexhat_z(float z) {
    float z2 = z * z;
    return MH_C * (1.0f - z2) * __expf(-0.5f * z2);
}
__device__ __forceinline__ float silu_f(float x) {
    return x / (1.0f + __expf(-x));
}
__device__ __forceinline__ unsigned short f2bf(float f) {
    union { __hip_bfloat16 b; unsigned short u; } cv;
    cv.b = __float2bfloat16(f);
    return cv.u;
}

// dst [N, 2*KH] bf16 = concat(a, b) along K. Compile-time KH -> shift div.
template<int KH>
__global__ void cast_cat_kernel(const float* __restrict__ a, const float* __restrict__ b,
                                unsigned short* __restrict__ dst, int N) {
    int idx4 = (blockIdx.x * 256 + threadIdx.x) * 4;
    constexpr int twoK = 2 * KH;
    if ((long)idx4 >= (long)N * twoK) return;
    int n = idx4 / twoK;
    int k = idx4 - n * twoK;
    const float* src = (k < KH) ? (a + (size_t)n * KH + k)
                                : (b + (size_t)n * KH + (k - KH));
    float4 v = *(const float4*)src;
    ushort4 o;
    o.x = f2bf(v.x); o.y = f2bf(v.y); o.z = f2bf(v.z); o.w = f2bf(v.w);
    *(ushort4*)(dst + (size_t)n * twoK + k) = o;
}

// dst [M, 2*D] bf16: k<D -> mexhat((x-t)/s), else silu(x)
template<int D>
__global__ void act_cat_kernel(const float* __restrict__ x, const float* __restrict__ trans,
                               const float* __restrict__ scale,
                               unsigned short* __restrict__ dst, int M) {
    int idx4 = (blockIdx.x * 256 + threadIdx.x) * 4;
    constexpr int twoD = 2 * D;
    if ((long)idx4 >= (long)M * twoD) return;
    int m = idx4 / twoD;
    int k = idx4 - m * twoD;
    float4 o;
    if (k < D) {
        float4 xv = *(const float4*)(x + (size_t)m * D + k);
        float4 t  = *(const float4*)(trans + k);
        float4 s  = *(const float4*)(scale + k);
        o.x = mexhat_z((xv.x - t.x) / s.x);
        o.y = mexhat_z((xv.y - t.y) / s.y);
        o.z = mexhat_z((xv.z - t.z) / s.z);
        o.w = mexhat_z((xv.w - t.w) / s.w);
    } else {
        int kk = k - D;
        float4 xv = *(const float4*)(x + (size_t)m * D + kk);
        o.x = silu_f(xv.x); o.y = silu_f(xv.y);
        o.z = silu_f(xv.z); o.w = silu_f(xv.w);
    }
    ushort4 u;
    u.x = f2bf(o.x); u.y = f2bf(o.y); u.z = f2bf(o.z); u.w = f2bf(o.w);
    *(ushort4*)(dst + (size_t)m * twoD + k) = u;
}

// C = A @ Bt^T.  A [M,K] bf16 row-major, Bt [N,K] bf16 row-major.
// 128x128 tile, BK=64, 256 threads = 4 waves in 2x2, each wave 64x64 via
// 2x2 mfma_f32_32x32x16_bf16. global_load_lds(16B) staging, XOR chunk
// swizzle on the GLOBAL source side (LDS dest stays wave-uniform-base +
// lane*16). LDS chunk (row, j) holds global k-chunk j ^ (row&7).
// A/B frag: [m=lane&31][k=(lane>>5)*8+j]. C/D: col=lane&31,
// row=(reg&3)+8*(reg>>2)+4*(lane>>5)  (m74/m101-verified).
// EPI=0: store fp32 C[M,N].  EPI=1: layer-2 activations -> A2 [M,2N] bf16.
template<int EPI>
__global__ __launch_bounds__(256)
void gemm_bt_kernel(const unsigned short* __restrict__ A,
                    const unsigned short* __restrict__ Bt,
                    float* __restrict__ C,
                    unsigned short* __restrict__ A2,
                    const float* __restrict__ trans,
                    const float* __restrict__ scale,
                    int N, int K) {
    __shared__ __align__(16) unsigned short sA[128 * 64];
    __shared__ __align__(16) unsigned short sB[128 * 64];

    const int tid  = threadIdx.x;
    const int lane = tid & 63;
    const int wv   = tid >> 6;
    const int wm   = wv >> 1;          // wave row 0..1 (64 rows each)
    const int wn   = wv & 1;           // wave col 0..1
    const int half = lane >> 5;        // 0..1
    const int l31  = lane & 31;
    const int rowBase = blockIdx.y * 128;
    const int colBase = blockIdx.x * 128;

    f32x16 acc[2][2] = {};

    for (int k0 = 0; k0 < K; k0 += 64) {
        // ---- stage A,B tiles: 128 rows x 8 chunks(16B) each ----
        #pragma unroll
        for (int r = 0; r < 4; ++r) {
            int c  = r * 256 + wv * 64 + lane;          // LDS chunk id
            int m  = c >> 3;                            // tile row
            int gk = ((c & 7) ^ (m & 7)) * 8;           // swizzled k offset (elems)
            const unsigned short* gpA = A  + (size_t)(rowBase + m) * K + k0 + gk;
            const unsigned short* gpB = Bt + (size_t)(colBase + m) * K + k0 + gk;
            unsigned short* lpA = sA + (size_t)(r * 256 + wv * 64) * 8; // wave-uniform
            unsigned short* lpB = sB + (size_t)(r * 256 + wv * 64) * 8;
            __builtin_amdgcn_global_load_lds(
                (const __attribute__((address_space(1))) void*)gpA,
                (__attribute__((address_space(3))) void*)lpA, 16, 0, 0);
            __builtin_amdgcn_global_load_lds(
                (const __attribute__((address_space(1))) void*)gpB,
                (__attribute__((address_space(3))) void*)lpB, 16, 0, 0);
        }
        __syncthreads();

        // ---- compute: 4 k-steps of 16, 2x2 MFMA(32x32x16) per wave ----
        #pragma unroll
        for (int s = 0; s < 4; ++s) {
            const int cc = s * 2 + half;                // k-chunk 0..7
            bf16x8 af[2], bfr[2];
            #pragma unroll
            for (int i = 0; i < 2; ++i) {
                int m = wm * 64 + i * 32 + l31;
                af[i] = *(const bf16x8*)(sA + (size_t)(m * 8 + (cc ^ (m & 7))) * 8);
            }
            #pragma unroll
            for (int j = 0; j < 2; ++j) {
                int n = wn * 64 + j * 32 + l31;
                bfr[j] = *(const bf16x8*)(sB + (size_t)(n * 8 + (cc ^ (n & 7))) * 8);
            }
            #pragma unroll
            for (int i = 0; i < 2; ++i)
                #pragma unroll
                for (int j = 0; j < 2; ++j)
                    acc[i][j] = __builtin_amdgcn_mfma_f32_32x32x16_bf16(
                        af[i], bfr[j], acc[i][j], 0, 0, 0);
        }
        __syncthreads();
    }

    // ---- epilogue: col=lane&31, row=(r&3)+8*(r>>2)+4*half ----
    #pragma unroll
    for (int j = 0; j < 2; ++j) {
        int col = colBase + wn * 64 + j * 32 + l31;
        float t = 0.f, sc = 1.f;
        if (EPI == 1) { t = trans[col]; sc = scale[col]; }
        #pragma unroll
        for (int i = 0; i < 2; ++i) {
            int rbase = rowBase + wm * 64 + i * 32 + 4 * half;
            #pragma unroll
            for (int r = 0; r < 16; ++r) {
                int row = rbase + (r & 3) + 8 * (r >> 2);
                float h = acc[i][j][r];
                if (EPI == 0) {
                    C[(size_t)row * N + col] = h;
                } else {
                    float z = (h - t) / sc;
                    size_t base = (size_t)row * (size_t)(2 * N) + col;
                    A2[base]     = f2bf(mexhat_z(z));
                    A2[base + N] = f2bf(silu_f(h));
                }
            }
        }
    }
}

extern "C" void kernel_launch(void* const* d_in, const int* in_sizes, int n_in,
                              void* d_out, int out_size, void* d_ws, size_t ws_size,
                              hipStream_t stream) {
    (void)in_sizes; (void)n_in; (void)out_size; (void)ws_size;
    const float* x       = (const float*)d_in[0];
    const float* scale1  = (const float*)d_in[1];
    const float* trans1  = (const float*)d_in[2];
    const float* wav_w1  = (const float*)d_in[3];
    const float* base_w1 = (const float*)d_in[4];
    const float* scale2  = (const float*)d_in[5];
    const float* trans2  = (const float*)d_in[6];
    const float* wav_w2  = (const float*)d_in[7];
    const float* base_w2 = (const float*)d_in[8];
    float* out = (float*)d_out;

    const int M = 8192, D = 1024, H = 4096;

    // workspace layout: W1c 16M | W2c 16M | A1 32M | A2 128M = 192 MiB
    unsigned short* W1c = (unsigned short*)d_ws;                 // [H, 2D]
    unsigned short* W2c = W1c + (size_t)H * 2 * D;               // [D, 2H]
    unsigned short* A1  = W2c + (size_t)D * 2 * H;               // [M, 2D]
    unsigned short* A2  = A1  + (size_t)M * 2 * D;               // [M, 2H]

    cast_cat_kernel<D><<<H * 2 * D / 4 / 256, 256, 0, stream>>>(wav_w1, base_w1, W1c, H);
    cast_cat_kernel<H><<<D * 2 * H / 4 / 256, 256, 0, stream>>>(wav_w2, base_w2, W2c, D);
    act_cat_kernel<D><<<M * 2 * D / 4 / 256, 256, 0, stream>>>(x, trans1, scale1, A1, M);

    // GEMM1: [M,2D] @ [H,2D]^T -> fused layer-2 activations -> A2 [M,2H]
    {
        dim3 grid(H / 128, M / 128);   // (32, 64)
        gemm_bt_kernel<1><<<grid, 256, 0, stream>>>(A1, W1c, nullptr, A2,
                                                    trans2, scale2, H, 2 * D);
    }
    // GEMM2: [M,2H] @ [D,2H]^T -> out fp32 [M,D]
    {
        dim3 grid(D / 128, M / 128);   // (8, 64)
        gemm_bt_kernel<0><<<grid, 256, 0, stream>>>(A2, W2c, out, nullptr,
                                                    nullptr, nullptr, D, 2 * H);
    }
}

// Round 3
// 532.801 us; speedup vs baseline: 1.1381x; 1.1381x over previous
//
#include <hip/hip_runtime.h>
#include <hip/hip_bf16.h>
#include <cstdint>
#include <cstddef>

// WaveKAN FFN: B=4 S=2048 D=1024 H=4096, M = B*S = 8192.
// layer1: h = mexhat((x-t1)/s1) @ wav_w1^T + silu(x) @ base_w1^T   [M,H]
// layer2: out = mexhat((h-t2)/s2) @ wav_w2^T + silu(h) @ base_w2^T [M,D]
// Concat branch-GEMMs along K -- INTERLEAVED: k=2i+p, p=0 wav-branch,
// p=1 silu-branch (packs GEMM1 epilogue stores into one u32 per element).
// bf16 MFMA 16x16x32, fp32 accum. Layer-2 activations fused into GEMM1
// epilogue (h never materialized). GEMM2 split-K=2 via fp32 atomics
// (exactly 2 adds/address -> commutative -> deterministic).
// R2 lesson: 32x32 MFMA regressed (4-way LDS bank alias within 32-lane
// halves + 132 VGPR occupancy drop). Staying on 16x16.

typedef __bf16 bf16x8 __attribute__((ext_vector_type(8)));
typedef float  f32x4  __attribute__((ext_vector_type(4)));
typedef unsigned short u16x8 __attribute__((ext_vector_type(8)));

#define MH_C 0.8673250705840776f   // 2/sqrt(3) * pi^-0.25

__device__ __forceinline__ float mexhat_z(float z) {
    float z2 = z * z;
    return MH_C * (1.0f - z2) * __expf(-0.5f * z2);
}
__device__ __forceinline__ float silu_f(float x) {
    return x / (1.0f + __expf(-x));
}
__device__ __forceinline__ unsigned short f2bf(float f) {
    union { __hip_bfloat16 b; unsigned short u; } cv;
    cv.b = __float2bfloat16(f);
    return cv.u;
}
__device__ __forceinline__ unsigned int pack2bf(float lo, float hi) {
    return (unsigned int)f2bf(lo) | ((unsigned int)f2bf(hi) << 16);
}

// dst [N, 2*KH] bf16, dst[n][2k+0]=a[n][k], dst[n][2k+1]=b[n][k]
template<int KH>
__global__ void cast_ilv_kernel(const float* __restrict__ a, const float* __restrict__ b,
                                unsigned short* __restrict__ dst, int N) {
    int idx4 = (blockIdx.x * 256 + threadIdx.x) * 4;
    if (idx4 >= N * KH) return;
    int n = idx4 / KH;              // KH is a power of two -> shift
    int k = idx4 - n * KH;
    float4 av = *(const float4*)(a + (size_t)n * KH + k);
    float4 bv = *(const float4*)(b + (size_t)n * KH + k);
    u16x8 o = { f2bf(av.x), f2bf(bv.x), f2bf(av.y), f2bf(bv.y),
                f2bf(av.z), f2bf(bv.z), f2bf(av.w), f2bf(bv.w) };
    *(u16x8*)(dst + (size_t)n * 2 * KH + 2 * k) = o;
}

// dst [M, 2*D] bf16: dst[m][2d+0]=mexhat((x-t)/s), dst[m][2d+1]=silu(x)
template<int D>
__global__ void act_ilv_kernel(const float* __restrict__ x, const float* __restrict__ trans,
                               const float* __restrict__ scale,
                               unsigned short* __restrict__ dst, int M) {
    int idx4 = (blockIdx.x * 256 + threadIdx.x) * 4;
    if (idx4 >= M * D) return;
    int m = idx4 / D;
    int d = idx4 - m * D;
    float4 xv = *(const float4*)(x + (size_t)m * D + d);
    float4 t  = *(const float4*)(trans + d);
    float4 s  = *(const float4*)(scale + d);
    u16x8 o = { f2bf(mexhat_z((xv.x - t.x) / s.x)), f2bf(silu_f(xv.x)),
                f2bf(mexhat_z((xv.y - t.y) / s.y)), f2bf(silu_f(xv.y)),
                f2bf(mexhat_z((xv.z - t.z) / s.z)), f2bf(silu_f(xv.z)),
                f2bf(mexhat_z((xv.w - t.w) / s.w)), f2bf(silu_f(xv.w)) };
    *(u16x8*)(dst + (size_t)m * 2 * D + 2 * d) = o;
}

// C += / A2 = f(A @ Bt^T).  A [M,Kfull] bf16 row-major, Bt [N,Kfull] bf16
// row-major. Block covers K range [blockIdx.z*Ks, (z+1)*Ks).
// 128x128 tile, BK=64, 4 waves 2x2, each wave 64x64 via 4x4
// mfma_f32_16x16x32_bf16. global_load_lds(16B) staging with XOR chunk
// swizzle on the GLOBAL source side (LDS dest stays wave-uniform-base +
// lane*16). LDS chunk (row, j) holds global k-chunk j ^ (row&7):
// per 16-lane quarter the 8 bank groups get 2 lanes each = conflict-free.
// EPI=0: unsafeAtomicAdd fp32 into C[M,N] (split-K; C pre-zeroed).
// EPI=1: layer-2 activations -> A2 [M, 2N] bf16 interleaved (u32 stores).
template<int EPI>
__global__ __launch_bounds__(256)
void gemm_bt_kernel(const unsigned short* __restrict__ A,
                    const unsigned short* __restrict__ Bt,
                    float* __restrict__ C,
                    unsigned short* __restrict__ A2,
                    const float* __restrict__ trans,
                    const float* __restrict__ scale,
                    int N, int Kfull, int Ks) {
    __shared__ __align__(16) unsigned short sA[128 * 64];
    __shared__ __align__(16) unsigned short sB[128 * 64];

    const int tid  = threadIdx.x;
    const int lane = tid & 63;
    const int wv   = tid >> 6;
    const int wm   = wv >> 1;          // wave row 0..1 (64 rows each)
    const int wn   = wv & 1;           // wave col 0..1
    const int rowBase = blockIdx.y * 128;
    const int colBase = blockIdx.x * 128;
    const int kStart  = blockIdx.z * Ks;

    f32x4 acc[4][4] = {};

    for (int k0 = kStart; k0 < kStart + Ks; k0 += 64) {
        // ---- stage A,B tiles: 128 rows x 8 chunks(16B) each ----
        #pragma unroll
        for (int r = 0; r < 4; ++r) {
            int c  = r * 256 + wv * 64 + lane;          // LDS chunk id
            int m  = c >> 3;                            // tile row
            int gk = ((c & 7) ^ (m & 7)) * 8;           // swizzled k offset (elems)
            const unsigned short* gpA = A  + (size_t)(rowBase + m) * Kfull + k0 + gk;
            const unsigned short* gpB = Bt + (size_t)(colBase + m) * Kfull + k0 + gk;
            unsigned short* lpA = sA + (size_t)(r * 256 + wv * 64) * 8; // wave-uniform
            unsigned short* lpB = sB + (size_t)(r * 256 + wv * 64) * 8;
            __builtin_amdgcn_global_load_lds(
                (const __attribute__((address_space(1))) void*)gpA,
                (__attribute__((address_space(3))) void*)lpA, 16, 0, 0);
            __builtin_amdgcn_global_load_lds(
                (const __attribute__((address_space(1))) void*)gpB,
                (__attribute__((address_space(3))) void*)lpB, 16, 0, 0);
        }
        __syncthreads();

        // ---- compute: 2 k-chunks of 32, 4x4 MFMA tiles per wave ----
        #pragma unroll
        for (int kk = 0; kk < 2; ++kk) {
            const int kcb = kk * 4 + (lane >> 4);       // k-chunk 0..7
            bf16x8 af[4], bfr[4];
            #pragma unroll
            for (int i = 0; i < 4; ++i) {
                int m = wm * 64 + i * 16 + (lane & 15);
                af[i] = *(const bf16x8*)(sA + (size_t)(m * 8 + (kcb ^ (m & 7))) * 8);
            }
            #pragma unroll
            for (int j = 0; j < 4; ++j) {
                int n = wn * 64 + j * 16 + (lane & 15);
                bfr[j] = *(const bf16x8*)(sB + (size_t)(n * 8 + (kcb ^ (n & 7))) * 8);
            }
            #pragma unroll
            for (int i = 0; i < 4; ++i)
                #pragma unroll
                for (int j = 0; j < 4; ++j)
                    acc[i][j] = __builtin_amdgcn_mfma_f32_16x16x32_bf16(
                        af[i], bfr[j], acc[i][j], 0, 0, 0);
        }
        __syncthreads();
    }

    // ---- epilogue: D[row=(lane>>4)*4+r][col=lane&15] (m89-verified) ----
    const int quad = lane >> 4;
    #pragma unroll
    for (int j = 0; j < 4; ++j) {
        const int col = colBase + wn * 64 + j * 16 + (lane & 15);
        float t = 0.f, sc = 1.f;
        if (EPI == 1) { t = trans[col]; sc = scale[col]; }
        #pragma unroll
        for (int i = 0; i < 4; ++i) {
            const int row0 = rowBase + wm * 64 + i * 16 + quad * 4;
            #pragma unroll
            for (int r = 0; r < 4; ++r) {
                float h = acc[i][j][r];
                if (EPI == 0) {
                    unsafeAtomicAdd(&C[(size_t)(row0 + r) * N + col], h);
                } else {
                    float z = (h - t) / sc;
                    unsigned int u = pack2bf(mexhat_z(z), silu_f(h));
                    *(unsigned int*)(A2 + (size_t)(row0 + r) * (size_t)(2 * N) + 2 * col) = u;
                }
            }
        }
    }
}

extern "C" void kernel_launch(void* const* d_in, const int* in_sizes, int n_in,
                              void* d_out, int out_size, void* d_ws, size_t ws_size,
                              hipStream_t stream) {
    (void)in_sizes; (void)n_in; (void)out_size; (void)ws_size;
    const float* x       = (const float*)d_in[0];
    const float* scale1  = (const float*)d_in[1];
    const float* trans1  = (const float*)d_in[2];
    const float* wav_w1  = (const float*)d_in[3];
    const float* base_w1 = (const float*)d_in[4];
    const float* scale2  = (const float*)d_in[5];
    const float* trans2  = (const float*)d_in[6];
    const float* wav_w2  = (const float*)d_in[7];
    const float* base_w2 = (const float*)d_in[8];
    float* out = (float*)d_out;

    const int M = 8192, D = 1024, H = 4096;

    // workspace layout: W1c 16M | W2c 16M | A1 32M | A2 128M = 192 MiB
    unsigned short* W1c = (unsigned short*)d_ws;                 // [H, 2D] ilv
    unsigned short* W2c = W1c + (size_t)H * 2 * D;               // [D, 2H] ilv
    unsigned short* A1  = W2c + (size_t)D * 2 * H;               // [M, 2D] ilv
    unsigned short* A2  = A1  + (size_t)M * 2 * D;               // [M, 2H] ilv

    // out is accumulated atomically by split-K GEMM2 -> zero it first
    hipMemsetAsync(d_out, 0, (size_t)M * D * sizeof(float), stream);

    cast_ilv_kernel<D><<<H * D / 4 / 256, 256, 0, stream>>>(wav_w1, base_w1, W1c, H);
    cast_ilv_kernel<H><<<D * H / 4 / 256, 256, 0, stream>>>(wav_w2, base_w2, W2c, D);
    act_ilv_kernel<D><<<M * D / 4 / 256, 256, 0, stream>>>(x, trans1, scale1, A1, M);

    // GEMM1: [M,2D] @ [H,2D]^T -> fused layer-2 activations -> A2 [M,2H]
    {
        dim3 grid(H / 128, M / 128, 1);   // (32, 64, 1)
        gemm_bt_kernel<1><<<grid, 256, 0, stream>>>(A1, W1c, nullptr, A2,
                                                    trans2, scale2, H, 2 * D, 2 * D);
    }
    // GEMM2: [M,2H] @ [D,2H]^T -> out fp32 [M,D], split-K=2 atomic accum
    {
        dim3 grid(D / 128, M / 128, 2);   // (8, 64, 2)
        gemm_bt_kernel<0><<<grid, 256, 0, stream>>>(A2, W2c, out, nullptr,
                                                    nullptr, nullptr, D, 2 * H, H);
    }
}

// Round 4
// 485.769 us; speedup vs baseline: 1.2483x; 1.0968x over previous
//
#include <hip/hip_runtime.h>
#include <hip/hip_bf16.h>
#include <cstdint>
#include <cstddef>

// WaveKAN FFN: B=4 S=2048 D=1024 H=4096, M = B*S = 8192.
// layer1: h = mexhat((x-t1)/s1) @ wav_w1^T + silu(x) @ base_w1^T   [M,H]
// layer2: out = mexhat((h-t2)/s2) @ wav_w2^T + silu(h) @ base_w2^T [M,D]
// Branch-GEMMs concatenated along K, INTERLEAVED (k=2i+p: p=0 wav, p=1 silu)
// so GEMM1's epilogue emits one packed u32 per h-element. bf16 MFMA
// 16x16x32, fp32 accum. Layer-2 activations fused into GEMM1 epilogue
// (h never materialized).
// R2 lesson: 32x32 MFMA structurally conflicts with BK-major LDS (32 lanes
// share a k-chunk column -> >=4-way bank alias) -> stay on 16x16.
// R3 lesson: split-K via device-scope fp32 atomics cost +48us on GEMM2
// (cross-XCD RMW serialization); residency was never the limiter -> plain
// single-pass GEMM2.

typedef __bf16 bf16x8 __attribute__((ext_vector_type(8)));
typedef float  f32x4  __attribute__((ext_vector_type(4)));
typedef unsigned short u16x8 __attribute__((ext_vector_type(8)));

#define MH_C 0.8673250705840776f   // 2/sqrt(3) * pi^-0.25

__device__ __forceinline__ float mexhat_z(float z) {
    float z2 = z * z;
    return MH_C * (1.0f - z2) * __expf(-0.5f * z2);
}
__device__ __forceinline__ float silu_f(float x) {
    return x / (1.0f + __expf(-x));
}
__device__ __forceinline__ unsigned short f2bf(float f) {
    union { __hip_bfloat16 b; unsigned short u; } cv;
    cv.b = __float2bfloat16(f);
    return cv.u;
}

// Fused prep: one dispatch does
//   job 0: W1c [H,2D] ilv <- bf16(wav_w1), bf16(base_w1)      (H*D/4 groups)
//   job 1: W2c [D,2H] ilv <- bf16(wav_w2), bf16(base_w2)      (D*H/4 groups)
//   job 2: A1  [M,2D] ilv <- mexhat((x-t1)/s1), silu(x)       (M*D/4 groups)
// All dims compile-time; group = 4 source elements -> one 16B store.
template<int D, int H, int M>
__global__ __launch_bounds__(256) void prep_kernel(
        const float* __restrict__ wav_w1, const float* __restrict__ base_w1,
        const float* __restrict__ wav_w2, const float* __restrict__ base_w2,
        const float* __restrict__ x, const float* __restrict__ trans1,
        const float* __restrict__ scale1,
        unsigned short* __restrict__ W1c, unsigned short* __restrict__ W2c,
        unsigned short* __restrict__ A1) {
    constexpr int G1 = H * D / 4;          // cast W1 groups
    constexpr int G2 = D * H / 4;          // cast W2 groups
    int g = blockIdx.x * 256 + threadIdx.x;
    if (g < G1) {
        int idx4 = g * 4;
        int n = idx4 / D, k = idx4 - n * D;
        float4 av = *(const float4*)(wav_w1  + (size_t)n * D + k);
        float4 bv = *(const float4*)(base_w1 + (size_t)n * D + k);
        u16x8 o = { f2bf(av.x), f2bf(bv.x), f2bf(av.y), f2bf(bv.y),
                    f2bf(av.z), f2bf(bv.z), f2bf(av.w), f2bf(bv.w) };
        *(u16x8*)(W1c + (size_t)n * 2 * D + 2 * k) = o;
    } else if (g < G1 + G2) {
        int idx4 = (g - G1) * 4;
        int n = idx4 / H, k = idx4 - n * H;
        float4 av = *(const float4*)(wav_w2  + (size_t)n * H + k);
        float4 bv = *(const float4*)(base_w2 + (size_t)n * H + k);
        u16x8 o = { f2bf(av.x), f2bf(bv.x), f2bf(av.y), f2bf(bv.y),
                    f2bf(av.z), f2bf(bv.z), f2bf(av.w), f2bf(bv.w) };
        *(u16x8*)(W2c + (size_t)n * 2 * H + 2 * k) = o;
    } else {
        int idx4 = (g - G1 - G2) * 4;
        int m = idx4 / D, d = idx4 - m * D;
        float4 xv = *(const float4*)(x + (size_t)m * D + d);
        float4 t  = *(const float4*)(trans1 + d);
        float4 s  = *(const float4*)(scale1 + d);
        u16x8 o = { f2bf(mexhat_z((xv.x - t.x) / s.x)), f2bf(silu_f(xv.x)),
                    f2bf(mexhat_z((xv.y - t.y) / s.y)), f2bf(silu_f(xv.y)),
                    f2bf(mexhat_z((xv.z - t.z) / s.z)), f2bf(silu_f(xv.z)),
                    f2bf(mexhat_z((xv.w - t.w) / s.w)), f2bf(silu_f(xv.w)) };
        *(u16x8*)(A1 + (size_t)m * 2 * D + 2 * d) = o;
    }
}

// C = A @ Bt^T (or fused activation thereof).
// A [M,K] bf16 row-major, Bt [N,K] bf16 row-major.
// 128x128 tile, BK=64, 4 waves 2x2, each wave 64x64 via 4x4
// mfma_f32_16x16x32_bf16. global_load_lds(16B) staging with XOR chunk
// swizzle on the GLOBAL source side (LDS dest stays wave-uniform-base +
// lane*16). LDS chunk (row, j) holds global k-chunk j ^ (row&7):
// per 16-lane quarter the 8 bank groups get 2 lanes each = conflict-free
// (2-way is free per m136; measured 0 SQ_LDS_BANK_CONFLICT).
// EPI=0: plain fp32 stores to C[M,N].
// EPI=1: layer-2 activations -> A2 [M, 2N] bf16 interleaved (u32 stores).
template<int EPI>
__global__ __launch_bounds__(256)
void gemm_bt_kernel(const unsigned short* __restrict__ A,
                    const unsigned short* __restrict__ Bt,
                    float* __restrict__ C,
                    unsigned short* __restrict__ A2,
                    const float* __restrict__ trans,
                    const float* __restrict__ scale,
                    int N, int K) {
    __shared__ __align__(16) unsigned short sA[128 * 64];
    __shared__ __align__(16) unsigned short sB[128 * 64];

    const int tid  = threadIdx.x;
    const int lane = tid & 63;
    const int wv   = tid >> 6;
    const int wm   = wv >> 1;          // wave row 0..1 (64 rows each)
    const int wn   = wv & 1;           // wave col 0..1
    const int rowBase = blockIdx.y * 128;
    const int colBase = blockIdx.x * 128;

    f32x4 acc[4][4] = {};

    for (int k0 = 0; k0 < K; k0 += 64) {
        // ---- stage A,B tiles: 128 rows x 8 chunks(16B) each ----
        #pragma unroll
        for (int r = 0; r < 4; ++r) {
            int c  = r * 256 + wv * 64 + lane;          // LDS chunk id
            int m  = c >> 3;                            // tile row
            int gk = ((c & 7) ^ (m & 7)) * 8;           // swizzled k offset (elems)
            const unsigned short* gpA = A  + (size_t)(rowBase + m) * K + k0 + gk;
            const unsigned short* gpB = Bt + (size_t)(colBase + m) * K + k0 + gk;
            unsigned short* lpA = sA + (size_t)(r * 256 + wv * 64) * 8; // wave-uniform
            unsigned short* lpB = sB + (size_t)(r * 256 + wv * 64) * 8;
            __builtin_amdgcn_global_load_lds(
                (const __attribute__((address_space(1))) void*)gpA,
                (__attribute__((address_space(3))) void*)lpA, 16, 0, 0);
            __builtin_amdgcn_global_load_lds(
                (const __attribute__((address_space(1))) void*)gpB,
                (__attribute__((address_space(3))) void*)lpB, 16, 0, 0);
        }
        __syncthreads();

        // ---- compute: 2 k-chunks of 32, 4x4 MFMA tiles per wave ----
        #pragma unroll
        for (int kk = 0; kk < 2; ++kk) {
            const int kcb = kk * 4 + (lane >> 4);       // k-chunk 0..7
            bf16x8 af[4], bfr[4];
            #pragma unroll
            for (int i = 0; i < 4; ++i) {
                int m = wm * 64 + i * 16 + (lane & 15);
                af[i] = *(const bf16x8*)(sA + (size_t)(m * 8 + (kcb ^ (m & 7))) * 8);
            }
            #pragma unroll
            for (int j = 0; j < 4; ++j) {
                int n = wn * 64 + j * 16 + (lane & 15);
                bfr[j] = *(const bf16x8*)(sB + (size_t)(n * 8 + (kcb ^ (n & 7))) * 8);
            }
            #pragma unroll
            for (int i = 0; i < 4; ++i)
                #pragma unroll
                for (int j = 0; j < 4; ++j)
                    acc[i][j] = __builtin_amdgcn_mfma_f32_16x16x32_bf16(
                        af[i], bfr[j], acc[i][j], 0, 0, 0);
        }
        __syncthreads();
    }

    // ---- epilogue: D[row=(lane>>4)*4+r][col=lane&15] (m89-verified) ----
    const int quad = lane >> 4;
    #pragma unroll
    for (int j = 0; j < 4; ++j) {
        const int col = colBase + wn * 64 + j * 16 + (lane & 15);
        float t = 0.f, sc = 1.f;
        if (EPI == 1) { t = trans[col]; sc = scale[col]; }
        #pragma unroll
        for (int i = 0; i < 4; ++i) {
            const int row0 = rowBase + wm * 64 + i * 16 + quad * 4;
            #pragma unroll
            for (int r = 0; r < 4; ++r) {
                float h = acc[i][j][r];
                if (EPI == 0) {
                    C[(size_t)(row0 + r) * N + col] = h;
                } else {
                    float z = (h - t) / sc;
                    unsigned int u = (unsigned int)f2bf(mexhat_z(z))
                                   | ((unsigned int)f2bf(silu_f(h)) << 16);
                    *(unsigned int*)(A2 + (size_t)(row0 + r) * (size_t)(2 * N)
                                        + 2 * col) = u;
                }
            }
        }
    }
}

extern "C" void kernel_launch(void* const* d_in, const int* in_sizes, int n_in,
                              void* d_out, int out_size, void* d_ws, size_t ws_size,
                              hipStream_t stream) {
    (void)in_sizes; (void)n_in; (void)out_size; (void)ws_size;
    const float* x       = (const float*)d_in[0];
    const float* scale1  = (const float*)d_in[1];
    const float* trans1  = (const float*)d_in[2];
    const float* wav_w1  = (const float*)d_in[3];
    const float* base_w1 = (const float*)d_in[4];
    const float* scale2  = (const float*)d_in[5];
    const float* trans2  = (const float*)d_in[6];
    const float* wav_w2  = (const float*)d_in[7];
    const float* base_w2 = (const float*)d_in[8];
    float* out = (float*)d_out;

    const int M = 8192, D = 1024, H = 4096;

    // workspace layout: W1c 16M | W2c 16M | A1 32M | A2 128M = 192 MiB
    unsigned short* W1c = (unsigned short*)d_ws;                 // [H, 2D] ilv
    unsigned short* W2c = W1c + (size_t)H * 2 * D;               // [D, 2H] ilv
    unsigned short* A1  = W2c + (size_t)D * 2 * H;               // [M, 2D] ilv
    unsigned short* A2  = A1  + (size_t)M * 2 * D;               // [M, 2H] ilv

    // fused prep: cast W1, cast W2, layer-1 activations (one dispatch)
    {
        const int groups = H * D / 4 + D * H / 4 + M * D / 4;   // 4,194,304
        prep_kernel<D, H, M><<<groups / 256, 256, 0, stream>>>(
            wav_w1, base_w1, wav_w2, base_w2, x, trans1, scale1, W1c, W2c, A1);
    }
    // GEMM1: [M,2D] @ [H,2D]^T -> fused layer-2 activations -> A2 [M,2H]
    {
        dim3 grid(H / 128, M / 128);   // (32, 64)
        gemm_bt_kernel<1><<<grid, 256, 0, stream>>>(A1, W1c, nullptr, A2,
                                                    trans2, scale2, H, 2 * D);
    }
    // GEMM2: [M,2H] @ [D,2H]^T -> out fp32 [M,D]
    {
        dim3 grid(D / 128, M / 128);   // (8, 64)
        gemm_bt_kernel<0><<<grid, 256, 0, stream>>>(A2, W2c, out, nullptr,
                                                    nullptr, nullptr, D, 2 * H);
    }
}

// Round 5
// 439.823 us; speedup vs baseline: 1.3787x; 1.1045x over previous
//
#include <hip/hip_runtime.h>
#include <hip/hip_bf16.h>
#include <cstdint>
#include <cstddef>

// WaveKAN FFN: B=4 S=2048 D=1024 H=4096, M = B*S = 8192.
// layer1: h = mexhat((x-t1)/s1) @ wav_w1^T + silu(x) @ base_w1^T   [M,H]
// layer2: out = mexhat((h-t2)/s2) @ wav_w2^T + silu(h) @ base_w2^T [M,D]
// Branch-GEMMs concatenated along K, INTERLEAVED (k=2i+p: p=0 wav, p=1 silu).
// bf16 MFMA 16x16x32, fp32 accum. Layer-2 activations fused into GEMM1
// epilogue (h never materialized).
// R2: 32x32 MFMA structurally conflicts with BK-major LDS -> 16x16.
// R3: split-K device atomics cost +48us (cross-XCD RMW) -> single-pass.
// R4->R5: GEMM1 & GEMM2 showed identical 29/53 Mfma/VALU profiles -> excess
// VALU is the main loop's rematerialized address math (compiler pinned
// VGPR=88). Hand-hoist staging pointers + LDS fragment offsets, and give
// the allocator room via __launch_bounds__(256,3) (~170 VGPR, 3 blk/CU).

typedef __bf16 bf16x8 __attribute__((ext_vector_type(8)));
typedef float  f32x4  __attribute__((ext_vector_type(4)));
typedef unsigned short u16x8 __attribute__((ext_vector_type(8)));

#define MH_C 0.8673250705840776f   // 2/sqrt(3) * pi^-0.25

__device__ __forceinline__ float mexhat_z(float z) {
    float z2 = z * z;
    return MH_C * (1.0f - z2) * __expf(-0.5f * z2);
}
__device__ __forceinline__ float silu_f(float x) {
    return x / (1.0f + __expf(-x));
}
__device__ __forceinline__ float silu_fast(float x) {
    // x * rcp(1+e^-x): v_rcp_f32 (~1ulp) instead of full fdiv sequence
    return x * __builtin_amdgcn_rcpf(1.0f + __expf(-x));
}
__device__ __forceinline__ unsigned short f2bf(float f) {
    union { __hip_bfloat16 b; unsigned short u; } cv;
    cv.b = __float2bfloat16(f);
    return cv.u;
}

// Fused prep: one dispatch does
//   job 0: W1c [H,2D] ilv <- bf16(wav_w1), bf16(base_w1)      (H*D/4 groups)
//   job 1: W2c [D,2H] ilv <- bf16(wav_w2), bf16(base_w2)      (D*H/4 groups)
//   job 2: A1  [M,2D] ilv <- mexhat((x-t1)/s1), silu(x)       (M*D/4 groups)
template<int D, int H, int M>
__global__ __launch_bounds__(256) void prep_kernel(
        const float* __restrict__ wav_w1, const float* __restrict__ base_w1,
        const float* __restrict__ wav_w2, const float* __restrict__ base_w2,
        const float* __restrict__ x, const float* __restrict__ trans1,
        const float* __restrict__ scale1,
        unsigned short* __restrict__ W1c, unsigned short* __restrict__ W2c,
        unsigned short* __restrict__ A1) {
    constexpr int G1 = H * D / 4;          // cast W1 groups
    constexpr int G2 = D * H / 4;          // cast W2 groups
    int g = blockIdx.x * 256 + threadIdx.x;
    if (g < G1) {
        int idx4 = g * 4;
        int n = idx4 / D, k = idx4 - n * D;
        float4 av = *(const float4*)(wav_w1  + (size_t)n * D + k);
        float4 bv = *(const float4*)(base_w1 + (size_t)n * D + k);
        u16x8 o = { f2bf(av.x), f2bf(bv.x), f2bf(av.y), f2bf(bv.y),
                    f2bf(av.z), f2bf(bv.z), f2bf(av.w), f2bf(bv.w) };
        *(u16x8*)(W1c + (size_t)n * 2 * D + 2 * k) = o;
    } else if (g < G1 + G2) {
        int idx4 = (g - G1) * 4;
        int n = idx4 / H, k = idx4 - n * H;
        float4 av = *(const float4*)(wav_w2  + (size_t)n * H + k);
        float4 bv = *(const float4*)(base_w2 + (size_t)n * H + k);
        u16x8 o = { f2bf(av.x), f2bf(bv.x), f2bf(av.y), f2bf(bv.y),
                    f2bf(av.z), f2bf(bv.z), f2bf(av.w), f2bf(bv.w) };
        *(u16x8*)(W2c + (size_t)n * 2 * H + 2 * k) = o;
    } else {
        int idx4 = (g - G1 - G2) * 4;
        int m = idx4 / D, d = idx4 - m * D;
        float4 xv = *(const float4*)(x + (size_t)m * D + d);
        float4 t  = *(const float4*)(trans1 + d);
        float4 s  = *(const float4*)(scale1 + d);
        u16x8 o = { f2bf(mexhat_z((xv.x - t.x) / s.x)), f2bf(silu_f(xv.x)),
                    f2bf(mexhat_z((xv.y - t.y) / s.y)), f2bf(silu_f(xv.y)),
                    f2bf(mexhat_z((xv.z - t.z) / s.z)), f2bf(silu_f(xv.z)),
                    f2bf(mexhat_z((xv.w - t.w) / s.w)), f2bf(silu_f(xv.w)) };
        *(u16x8*)(A1 + (size_t)m * 2 * D + 2 * d) = o;
    }
}

// C = A @ Bt^T (or fused activation thereof).
// A [M,K] bf16 row-major, Bt [N,K] bf16 row-major.
// 128x128 tile, BK=64, 4 waves 2x2, each wave 64x64 via 4x4
// mfma_f32_16x16x32_bf16. global_load_lds(16B) staging with XOR chunk
// swizzle on the GLOBAL source side; LDS chunk (row,j) holds global
// k-chunk j^(row&7): per 16-lane quarter 8 bank-groups x 2 lanes = free.
// All staging pointers and fragment LDS offsets are hoisted out of the
// K-loop; launch_bounds(256,3) gives the allocator room to keep them live.
// EPI=0: plain fp32 stores.  EPI=1: layer-2 acts -> A2 [M,2N] bf16 ilv.
template<int EPI>
__global__ __launch_bounds__(256, 3)
void gemm_bt_kernel(const unsigned short* __restrict__ A,
                    const unsigned short* __restrict__ Bt,
                    float* __restrict__ C,
                    unsigned short* __restrict__ A2,
                    const float* __restrict__ trans,
                    const float* __restrict__ scale,
                    int N, int K) {
    __shared__ __align__(16) unsigned short sA[128 * 64];
    __shared__ __align__(16) unsigned short sB[128 * 64];

    const int tid  = threadIdx.x;
    const int lane = tid & 63;
    const int wv   = tid >> 6;
    const int wm   = wv >> 1;          // wave row 0..1 (64 rows each)
    const int wn   = wv & 1;           // wave col 0..1
    const int quad = lane >> 4;        // 0..3
    const int l15  = lane & 15;
    const int rowBase = blockIdx.y * 128;
    const int colBase = blockIdx.x * 128;

    // ---- hoisted staging addresses (loop-invariant except +k0) ----
    const unsigned short* gA[4];
    const unsigned short* gB[4];
    unsigned short* lA[4];
    unsigned short* lB[4];
    #pragma unroll
    for (int r = 0; r < 4; ++r) {
        int c  = r * 256 + wv * 64 + lane;          // LDS chunk id
        int m  = c >> 3;                            // tile row
        int gk = ((c & 7) ^ (m & 7)) * 8;           // swizzled k offset (elems)
        gA[r] = A  + (size_t)(rowBase + m) * K + gk;
        gB[r] = Bt + (size_t)(colBase + m) * K + gk;
        lA[r] = sA + (size_t)(r * 256 + wv * 64) * 8;   // wave-uniform base
        lB[r] = sB + (size_t)(r * 256 + wv * 64) * 8;
    }

    // ---- hoisted fragment LDS offsets (elements) ----
    int offA[2][4], offB[2][4];
    #pragma unroll
    for (int kk = 0; kk < 2; ++kk) {
        int kcb = kk * 4 + quad;
        #pragma unroll
        for (int i = 0; i < 4; ++i) {
            int m = wm * 64 + i * 16 + l15;
            offA[kk][i] = (m * 8 + (kcb ^ (m & 7))) * 8;
            int n = wn * 64 + i * 16 + l15;
            offB[kk][i] = (n * 8 + (kcb ^ (n & 7))) * 8;
        }
    }

    f32x4 acc[4][4] = {};

    for (int k0 = 0; k0 < K; k0 += 64) {
        #pragma unroll
        for (int r = 0; r < 4; ++r) {
            __builtin_amdgcn_global_load_lds(
                (const __attribute__((address_space(1))) void*)(gA[r] + k0),
                (__attribute__((address_space(3))) void*)lA[r], 16, 0, 0);
            __builtin_amdgcn_global_load_lds(
                (const __attribute__((address_space(1))) void*)(gB[r] + k0),
                (__attribute__((address_space(3))) void*)lB[r], 16, 0, 0);
        }
        __syncthreads();

        #pragma unroll
        for (int kk = 0; kk < 2; ++kk) {
            bf16x8 af[4], bfr[4];
            #pragma unroll
            for (int i = 0; i < 4; ++i) {
                af[i]  = *(const bf16x8*)(sA + offA[kk][i]);
                bfr[i] = *(const bf16x8*)(sB + offB[kk][i]);
            }
            #pragma unroll
            for (int i = 0; i < 4; ++i)
                #pragma unroll
                for (int j = 0; j < 4; ++j)
                    acc[i][j] = __builtin_amdgcn_mfma_f32_16x16x32_bf16(
                        af[i], bfr[j], acc[i][j], 0, 0, 0);
        }
        __syncthreads();
    }

    // ---- epilogue: D[row=(lane>>4)*4+r][col=lane&15] (m89-verified) ----
    #pragma unroll
    for (int j = 0; j < 4; ++j) {
        const int col = colBase + wn * 64 + j * 16 + l15;
        float t = 0.f, rsc = 1.f;
        if (EPI == 1) { t = trans[col]; rsc = __builtin_amdgcn_rcpf(scale[col]); }
        #pragma unroll
        for (int i = 0; i < 4; ++i) {
            const int row0 = rowBase + wm * 64 + i * 16 + quad * 4;
            #pragma unroll
            for (int r = 0; r < 4; ++r) {
                float h = acc[i][j][r];
                if (EPI == 0) {
                    C[(size_t)(row0 + r) * N + col] = h;
                } else {
                    float z = (h - t) * rsc;
                    unsigned int u = (unsigned int)f2bf(mexhat_z(z))
                                   | ((unsigned int)f2bf(silu_fast(h)) << 16);
                    *(unsigned int*)(A2 + (size_t)(row0 + r) * (size_t)(2 * N)
                                        + 2 * col) = u;
                }
            }
        }
    }
}

extern "C" void kernel_launch(void* const* d_in, const int* in_sizes, int n_in,
                              void* d_out, int out_size, void* d_ws, size_t ws_size,
                              hipStream_t stream) {
    (void)in_sizes; (void)n_in; (void)out_size; (void)ws_size;
    const float* x       = (const float*)d_in[0];
    const float* scale1  = (const float*)d_in[1];
    const float* trans1  = (const float*)d_in[2];
    const float* wav_w1  = (const float*)d_in[3];
    const float* base_w1 = (const float*)d_in[4];
    const float* scale2  = (const float*)d_in[5];
    const float* trans2  = (const float*)d_in[6];
    const float* wav_w2  = (const float*)d_in[7];
    const float* base_w2 = (const float*)d_in[8];
    float* out = (float*)d_out;

    const int M = 8192, D = 1024, H = 4096;

    // workspace layout: W1c 16M | W2c 16M | A1 32M | A2 128M = 192 MiB
    unsigned short* W1c = (unsigned short*)d_ws;                 // [H, 2D] ilv
    unsigned short* W2c = W1c + (size_t)H * 2 * D;               // [D, 2H] ilv
    unsigned short* A1  = W2c + (size_t)D * 2 * H;               // [M, 2D] ilv
    unsigned short* A2  = A1  + (size_t)M * 2 * D;               // [M, 2H] ilv

    // fused prep: cast W1, cast W2, layer-1 activations (one dispatch)
    {
        const int groups = H * D / 4 + D * H / 4 + M * D / 4;   // 4,194,304
        prep_kernel<D, H, M><<<groups / 256, 256, 0, stream>>>(
            wav_w1, base_w1, wav_w2, base_w2, x, trans1, scale1, W1c, W2c, A1);
    }
    // GEMM1: [M,2D] @ [H,2D]^T -> fused layer-2 activations -> A2 [M,2H]
    {
        dim3 grid(H / 128, M / 128);   // (32, 64)
        gemm_bt_kernel<1><<<grid, 256, 0, stream>>>(A1, W1c, nullptr, A2,
                                                    trans2, scale2, H, 2 * D);
    }
    // GEMM2: [M,2H] @ [D,2H]^T -> out fp32 [M,D]
    {
        dim3 grid(D / 128, M / 128);   // (8, 64)
        gemm_bt_kernel<0><<<grid, 256, 0, stream>>>(A2, W2c, out, nullptr,
                                                    nullptr, nullptr, D, 2 * H);
    }
}